// Round 16
// baseline (234.366 us; speedup 1.0000x reference)
//
#include <hip/hip_runtime.h>

#define NN 20000
#define NE 160000
#define NEF 180000          // edges + self loops
#define NB1 ((NN + 255) / 256)   // 79 scan blocks

typedef long long ll;
typedef __attribute__((ext_vector_type(4))) float f32x4;
typedef __attribute__((ext_vector_type(8))) short s16x8;

// ---------- bf16 helpers (round-to-nearest-even) ----------
static __device__ __forceinline__ float b2f(ushort u) {
  return __uint_as_float(((unsigned)u) << 16);
}
static __device__ __forceinline__ ushort f2b(float f) {
  unsigned u = __float_as_uint(f);
  return (ushort)((u + 0x7fffu + ((u >> 16) & 1u)) >> 16);
}

// ---------- bf16 MFMA GEMM: C[M,N] = A[M,K] @ Bt[N,K]^T (+bias) ----------
// 4 waves in 2x2; wave tile = (16*MF) x (16*NF); no LDS; compile-time K.
template<int MF, int NF, int K, bool F32OUT>
__global__ __launch_bounds__(256) void gemm_mfma(
    const ushort* __restrict__ A, const ushort* __restrict__ Bt,
    const float* __restrict__ bias, void* __restrict__ Cv,
    int M, int N, int lda)
{
  const int wid  = threadIdx.x >> 6;
  const int lane = threadIdx.x & 63;
  const int wr = wid >> 1, wc = wid & 1;
  const int bm = blockIdx.y * (32 * MF) + wr * (16 * MF);
  const int bn = blockIdx.x * (32 * NF) + wc * (16 * NF);
  const int lr = lane & 15;
  const int ko = (lane >> 4) * 8;

  const ushort* pa[MF];
  const ushort* pb[NF];
  #pragma unroll
  for (int i = 0; i < MF; i++) {
    int r = min(bm + i * 16 + lr, M - 1);
    pa[i] = A + (ll)r * lda + ko;
  }
  #pragma unroll
  for (int j = 0; j < NF; j++) {
    int c = min(bn + j * 16 + lr, N - 1);
    pb[j] = Bt + (ll)c * K + ko;
  }

  f32x4 acc[MF][NF];
  #pragma unroll
  for (int i = 0; i < MF; i++)
    #pragma unroll
    for (int j = 0; j < NF; j++) acc[i][j] = {0.f, 0.f, 0.f, 0.f};

  #pragma unroll
  for (int k = 0; k < K; k += 32) {
    s16x8 af[MF], bf[NF];
    #pragma unroll
    for (int i = 0; i < MF; i++) af[i] = *(const s16x8*)(pa[i] + k);
    #pragma unroll
    for (int j = 0; j < NF; j++) bf[j] = *(const s16x8*)(pb[j] + k);
    #pragma unroll
    for (int i = 0; i < MF; i++)
      #pragma unroll
      for (int j = 0; j < NF; j++)
        acc[i][j] = __builtin_amdgcn_mfma_f32_16x16x32_bf16(af[i], bf[j], acc[i][j], 0, 0, 0);
  }

  const int rq = (lane >> 4) * 4;
  #pragma unroll
  for (int i = 0; i < MF; i++) {
    #pragma unroll
    for (int j = 0; j < NF; j++) {
      int col = bn + j * 16 + lr;
      if (col >= N) continue;
      float bv = bias ? bias[col] : 0.f;
      int rbase = bm + i * 16 + rq;
      #pragma unroll
      for (int r = 0; r < 4; r++) {
        int row = rbase + r;
        if (row >= M) continue;
        float v = acc[i][j][r] + bv;
        if (F32OUT) ((float*)Cv)[(ll)row * N + col] = v;
        else        ((ushort*)Cv)[(ll)row * N + col] = f2b(v);
      }
    }
  }
}

// ---------- fused GAT-apply + GCN1 GEMM (all-heads A prestage + B prefetch) ----
// hw64 = relu(agg @ blockdiag(W_g) + b_g) @ W_c1, never materializing gat.
__global__ __launch_bounds__(256) void k_gat_apply_gcn1(
    const ushort* __restrict__ agg,   // [NN,1024] bf16 (8 heads x 128)
    const ushort* __restrict__ BtG,   // [1024,128]: BtG[c*128+k] = W_g[k,c]
    const ushort* __restrict__ Btc1,  // [64,1024]:  Btc1[n*1024+k] = W_c1[k,n]
    const float* __restrict__ b_g,    // [1024]
    ushort* __restrict__ hw64)        // [NN,64] bf16
{
  __shared__ ushort At[2][32 * 128];  // A windows, granule^=(row&7) swizzle
  __shared__ ushort gt[2][32][72];    // gat tiles (+pad)
  const int t    = threadIdx.x;
  const int wc   = t >> 6;            // wave = col strip 0..3
  const int lane = t & 63;
  const int bm = blockIdx.x * 32;
  const int lr = lane & 15;
  const int q  = lane >> 4;
  const int ko = q * 8;
  const int rq = q * 4;

  // staging identity: thread = (row 0..31, colgroup 0..7), 2x16B granules
  const int srow = t >> 3;
  const int scg  = t & 7;
  const ushort* sg = agg + (ll)min(bm + srow, NN - 1) * 1024 + scg * 16;
  const int w0 = srow * 128 + (((2 * scg)     ^ (srow & 7)) * 8);
  const int w1 = srow * 128 + (((2 * scg + 1) ^ (srow & 7)) * 8);

  // ---- stage ALL heads' A into registers upfront ----
  s16x8 ar[8][2];
  #pragma unroll
  for (int h = 0; h < 8; h++) {
    ar[h][0] = *(const s16x8*)(sg + h * 128);
    ar[h][1] = *(const s16x8*)(sg + h * 128 + 8);
  }

  // ---- B double-buffer registers; preload ct = 0 ----
  s16x8 b1[2][4];                     // phase-1 W_g fragments
  s16x8 b2[2][2];                     // phase-2 W_c1 fragments
  float bvs[2];
  {
    const int cg = wc * 16 + lr;
    const ushort* pb = BtG + (ll)cg * 128 + ko;
    b1[0][0] = *(const s16x8*)(pb);
    b1[0][1] = *(const s16x8*)(pb + 32);
    b1[0][2] = *(const s16x8*)(pb + 64);
    b1[0][3] = *(const s16x8*)(pb + 96);
    const ushort* qb = Btc1 + (ll)cg * 1024 + ko;
    b2[0][0] = *(const s16x8*)(qb);
    b2[0][1] = *(const s16x8*)(qb + 32);
    bvs[0] = b_g[cg];
  }

  f32x4 o0 = {0.f, 0.f, 0.f, 0.f}, o1 = o0;

  #pragma unroll
  for (int h = 0; h < 8; h++) {
    *(s16x8*)&At[h & 1][w0] = ar[h][0];
    *(s16x8*)&At[h & 1][w1] = ar[h][1];
    __syncthreads();
    #pragma unroll
    for (int it = 0; it < 2; it++) {
      const int ct = 2 * h + it;       // compile-time
      const int cur = it, nxt = it ^ 1;
      if (ct < 15) {                   // prefetch next ct's B + bias
        const int cg2 = (ct + 1) * 64 + wc * 16 + lr;
        const ushort* pb2 = BtG + (ll)cg2 * 128 + ko;
        b1[nxt][0] = *(const s16x8*)(pb2);
        b1[nxt][1] = *(const s16x8*)(pb2 + 32);
        b1[nxt][2] = *(const s16x8*)(pb2 + 64);
        b1[nxt][3] = *(const s16x8*)(pb2 + 96);
        const ushort* qb2 = Btc1 + (ll)(wc * 16 + lr) * 1024 + (ct + 1) * 64 + ko;
        b2[nxt][0] = *(const s16x8*)(qb2);
        b2[nxt][1] = *(const s16x8*)(qb2 + 32);
        bvs[nxt] = b_g[cg2];
      }
      f32x4 g0 = {0.f, 0.f, 0.f, 0.f}, g1 = g0;
      #pragma unroll
      for (int k = 0; k < 4; k++) {
        const int gi = (k * 4 + q) ^ (lr & 7);
        s16x8 a0 = *(const s16x8*)&At[h & 1][lr        * 128 + gi * 8];
        s16x8 a1 = *(const s16x8*)&At[h & 1][(16 + lr) * 128 + gi * 8];
        g0 = __builtin_amdgcn_mfma_f32_16x16x32_bf16(a0, b1[cur][k], g0, 0, 0, 0);
        g1 = __builtin_amdgcn_mfma_f32_16x16x32_bf16(a1, b1[cur][k], g1, 0, 0, 0);
      }
      float bv = bvs[cur];
      #pragma unroll
      for (int r = 0; r < 4; r++) {
        gt[it][rq + r][wc * 16 + lr]      = f2b(fmaxf(g0[r] + bv, 0.f));
        gt[it][16 + rq + r][wc * 16 + lr] = f2b(fmaxf(g1[r] + bv, 0.f));
      }
      __syncthreads();
      {
        s16x8 a0 = *(const s16x8*)&gt[it][lr][ko];
        s16x8 a1 = *(const s16x8*)&gt[it][16 + lr][ko];
        o0 = __builtin_amdgcn_mfma_f32_16x16x32_bf16(a0, b2[cur][0], o0, 0, 0, 0);
        o1 = __builtin_amdgcn_mfma_f32_16x16x32_bf16(a1, b2[cur][0], o1, 0, 0, 0);
        s16x8 a2 = *(const s16x8*)&gt[it][lr][32 + ko];
        s16x8 a3 = *(const s16x8*)&gt[it][16 + lr][32 + ko];
        o0 = __builtin_amdgcn_mfma_f32_16x16x32_bf16(a2, b2[cur][1], o0, 0, 0, 0);
        o1 = __builtin_amdgcn_mfma_f32_16x16x32_bf16(a3, b2[cur][1], o1, 0, 0, 0);
      }
    }
  }
  int col = wc * 16 + lr;
  #pragma unroll
  for (int r = 0; r < 4; r++) {
    int row0 = bm + rq + r, row1 = bm + 16 + rq + r;
    if (row0 < NN) hw64[(ll)row0 * 64 + col] = f2b(o0[r]);
    if (row1 < NN) hw64[(ll)row1 * 64 + col] = f2b(o1[r]);
  }
}

// ---------- fused setup: x cast, weight transpose+cast, bias packs, watt, zero icnt --
struct PrepEnt { const float* W; ushort* Bt; int N; int K; int base; };
struct Prep { PrepEnt e[8]; int total; };

__global__ void k_setup(const float* __restrict__ x, ushort* __restrict__ xb, Prep p,
                        const float* __restrict__ b_res, const float* __restrict__ b_l1,
                        const float* __restrict__ b_l2, float* __restrict__ bias192,
                        float* __restrict__ bias256,
                        const float* __restrict__ W_g, const float* __restrict__ att_s,
                        const float* __restrict__ att_d, ushort* __restrict__ watt_t,
                        int* __restrict__ icnt) {
  ll t = (ll)blockIdx.x * 256 + threadIdx.x;
  const ll T0 = (ll)NN * 64;          // x cast: 4 floats each
  if (t < T0) {
    ll i = t * 4;
    float4 v = *(const float4*)(x + i);
    ushort4 o;
    o.x = f2b(v.x); o.y = f2b(v.y); o.z = f2b(v.z); o.w = f2b(v.w);
    *(ushort4*)(xb + i) = o;
    return;
  }
  t -= T0;
  if (t < p.total) {
    int tt = (int)t;
    #pragma unroll
    for (int i = 0; i < 8; i++) {
      int sz = p.e[i].N * p.e[i].K;
      if (tt >= p.e[i].base && tt < p.e[i].base + sz) {
        int loc = tt - p.e[i].base;
        int n = loc / p.e[i].K, k = loc - n * p.e[i].K;
        p.e[i].Bt[loc] = f2b(p.e[i].W[(ll)k * p.e[i].N + n]);
      }
    }
    return;
  }
  t -= p.total;
  if (t < 256) {
    int tt = (int)t;
    if (tt < 64) bias192[tt] = b_res[tt];
    else if (tt < 128) bias192[tt] = 0.f;
    else if (tt < 192) bias192[tt] = b_l1[tt - 128];
    bias256[tt] = (tt < 128) ? 0.f : b_l2[tt - 128];
    return;
  }
  t -= 256;
  if (t < 2048) {   // watt_t[col][k] = bf16( dot(W_g[k, h*128: ], att_{s|d}[h, :]) )
    int k = (int)t >> 4;
    int col = (int)t & 15;
    int h = col & 7;
    const float* av = (col < 8) ? (att_s + h * 128) : (att_d + h * 128);
    const float* wrow = W_g + (ll)k * 1024 + h * 128;
    float s = 0.f;
    for (int j = 0; j < 128; j++) s += wrow[j] * av[j];
    watt_t[col * 128 + k] = f2b(s);
    return;
  }
  t -= 2048;
  if (t < NN) icnt[t] = 0;
}

// ---------- CSR build ----------
__global__ void k_counti(const int* __restrict__ dst, int* __restrict__ icnt) {
  int e = blockIdx.x * 256 + threadIdx.x;
  if (e < NE) atomicAdd(&icnt[dst[e]], 1);
}

__global__ __launch_bounds__(256) void k_scan1(const int* __restrict__ icnt,
                                               int* __restrict__ rowptr,
                                               int* __restrict__ bsum) {
  __shared__ int sd[256];
  int t = threadIdx.x;
  int i = blockIdx.x * 256 + t;
  int v = (i < NN) ? icnt[i] + 1 : 0;   // +1 self loop
  sd[t] = v;
  __syncthreads();
  #pragma unroll
  for (int o = 1; o < 256; o <<= 1) {
    int u = (t >= o) ? sd[t - o] : 0;
    __syncthreads();
    sd[t] += u;
    __syncthreads();
  }
  if (i < NN) rowptr[i] = sd[t] - v;    // block-local exclusive
  if (t == 255) bsum[blockIdx.x] = sd[255];
}

__global__ __launch_bounds__(128) void k_scan2(const int* __restrict__ bsum,
                                               int* __restrict__ boff) {
  __shared__ int sd[128];
  int t = threadIdx.x;
  int v = (t < NB1) ? bsum[t] : 0;
  sd[t] = v;
  __syncthreads();
  #pragma unroll
  for (int o = 1; o < 128; o <<= 1) {
    int u = (t >= o) ? sd[t - o] : 0;
    __syncthreads();
    sd[t] += u;
    __syncthreads();
  }
  if (t < NB1) boff[t] = sd[t] - v;
}

__global__ void k_scan3(int* __restrict__ rowptr, const int* __restrict__ boff,
                        int* __restrict__ cur, const int* __restrict__ icnt,
                        float* __restrict__ dinv) {
  int i = blockIdx.x * 256 + threadIdx.x;
  if (i >= NN) return;
  int r = rowptr[i] + boff[i >> 8];
  rowptr[i] = r;
  cur[i] = r;
  dinv[i] = rsqrtf((float)icnt[i] + 1.0f);
  if (i == 0) rowptr[NN] = NEF;
}

__global__ void k_scatter(const int* __restrict__ dst, int* __restrict__ cur,
                          int* __restrict__ eid) {
  int t = blockIdx.x * 256 + threadIdx.x;
  if (t >= NEF) return;
  int d = (t < NE) ? dst[t] : t - NE;
  int p = atomicAdd(&cur[d], 1);
  eid[p] = t;
}

// ---------- SAGE aggregation: shuffle-staged gather + mean + lin_r + relu (+res) --
// SCORES (C=128 only): fused GAT score epilogue asd[n,16] = h2[n,:] @ watt^T
template<int C, int STRIDE, bool ADD_RES, bool SCORES>
__global__ __launch_bounds__(256) void k_sage_csr(
    const int* __restrict__ rowptr, const int* __restrict__ eid,
    const int* __restrict__ src, const ushort* __restrict__ feat,
    const ushort* __restrict__ linr, const ushort* __restrict__ resx,
    ushort* __restrict__ out, const ushort* __restrict__ watt,
    float* __restrict__ asd)
{
  __shared__ ushort wat[2048];         // [16][128] bf16 (used if SCORES)
  if (SCORES) {
    for (int i = threadIdx.x; i < 2048; i += 256) wat[i] = watt[i];
    __syncthreads();
  }
  int node = blockIdx.x * 4 + (threadIdx.x >> 6);
  int lane = threadIdx.x & 63;
  if (node >= NN) return;
  int b = rowptr[node], e = rowptr[node + 1];
  float a0 = 0.f, a1 = 0.f;
  int n = 0;
  for (int base = b; base < e; base += 64) {
    int m = min(64, e - base);
    int sreg = -1;
    if (lane < m) {
      int ed = eid[base + lane];
      sreg = (ed < NE) ? src[ed] : -1;   // self loop excluded from SAGE mean
    }
    for (int i = 0; i < m; i++) {
      int s = __shfl(sreg, i);
      if (s >= 0) {
        a0 += b2f(feat[(ll)s * STRIDE + lane]);
        if (C == 128) a1 += b2f(feat[(ll)s * STRIDE + lane + 64]);
        n++;
      }
    }
  }
  float inv = 1.f / fmaxf((float)n, 1.f);
  float v0 = a0 * inv + b2f(linr[(ll)node * STRIDE + lane]);
  v0 = fmaxf(v0, 0.f);
  if (ADD_RES) v0 += b2f(resx[(ll)node * STRIDE + lane]);
  out[(ll)node * C + lane] = f2b(v0);
  float v1 = 0.f;
  if (C == 128) {
    v1 = a1 * inv + b2f(linr[(ll)node * STRIDE + lane + 64]);
    v1 = fmaxf(v1, 0.f);
    out[(ll)node * C + lane + 64] = f2b(v1);
  }
  if (SCORES && C == 128) {            // 16 wave-reduced dot products
    #pragma unroll
    for (int j = 0; j < 16; j++) {
      float p = v0 * b2f(wat[j * 128 + lane]) + v1 * b2f(wat[j * 128 + lane + 64]);
      #pragma unroll
      for (int o = 32; o > 0; o >>= 1) p += __shfl_down(p, o);
      if (lane == 0) asd[(ll)node * 16 + j] = p;
    }
  }
}

// ---------- fused GAT softmax + aggregation in h2-space ----------
// agg[n,h,c] = (1/den_h) sum_e exp(score_e,h - max_h) * h2[src_e, c]
// Block per node, 128 threads. Flash-style online max/sum across 64-edge chunks.
__global__ __launch_bounds__(128) void k_gat_agg(
    const int* __restrict__ rowptr, const int* __restrict__ eid,
    const int* __restrict__ src, const float* __restrict__ asd,
    const ushort* __restrict__ h2b, ushort* __restrict__ agg)
{
  __shared__ int s_l[64];
  __shared__ float al[64 * 8];
  __shared__ float adl[8];
  __shared__ float mrun[8], srun[8], fac[8];
  int node = blockIdx.x;
  int c = threadIdx.x;                 // channel 0..127
  int b = rowptr[node], e = rowptr[node + 1];
  if (c < 8) {
    adl[c] = asd[(ll)node * 16 + 8 + c];
    mrun[c] = -3.0e38f;
    srun[c] = 0.f;
  }
  float acc[8] = {0.f, 0.f, 0.f, 0.f, 0.f, 0.f, 0.f, 0.f};
  for (int c0 = b; c0 < e; c0 += 64) {
    int m = min(64, e - c0);
    if (c < m) { int ed = eid[c0 + c]; s_l[c] = (ed < NE) ? src[ed] : node; }
    __syncthreads();
    // scores (leaky-relu) for this chunk
    for (int idx = c; idx < m * 8; idx += 128) {
      int i = idx >> 3, h = idx & 7;
      float v = asd[(ll)s_l[i] * 16 + h] + adl[h];
      al[idx] = (v > 0.f) ? v : 0.2f * v;
    }
    __syncthreads();
    // per-head chunk max + rescale factor (threads 0..7)
    if (c < 8) {
      float cm = mrun[c];
      for (int i = 0; i < m; i++) cm = fmaxf(cm, al[i * 8 + c]);
      fac[c] = __expf(mrun[c] - cm);
      mrun[c] = cm;
    }
    __syncthreads();
    // exponentiate in place
    for (int idx = c; idx < m * 8; idx += 128) {
      int h = idx & 7;
      al[idx] = __expf(al[idx] - mrun[h]);
    }
    __syncthreads();
    // per-head sum update
    if (c < 8) {
      float cs = 0.f;
      for (int i = 0; i < m; i++) cs += al[i * 8 + c];
      srun[c] = srun[c] * fac[c] + cs;
    }
    // rescale accumulators, then aggregate this chunk
    #pragma unroll
    for (int h = 0; h < 8; h++) acc[h] *= fac[h];
    for (int i = 0; i < m; i++) {
      float v = b2f(h2b[(ll)s_l[i] * 128 + c]);
      float4 aa = *(const float4*)&al[i * 8];
      float4 ab = *(const float4*)&al[i * 8 + 4];
      acc[0] = fmaf(aa.x, v, acc[0]);
      acc[1] = fmaf(aa.y, v, acc[1]);
      acc[2] = fmaf(aa.z, v, acc[2]);
      acc[3] = fmaf(aa.w, v, acc[3]);
      acc[4] = fmaf(ab.x, v, acc[4]);
      acc[5] = fmaf(ab.y, v, acc[5]);
      acc[6] = fmaf(ab.z, v, acc[6]);
      acc[7] = fmaf(ab.w, v, acc[7]);
    }
    __syncthreads();
  }
  #pragma unroll
  for (int h = 0; h < 8; h++)
    agg[(ll)node * 1024 + h * 128 + c] = f2b(acc[h] / srun[h]);
}

// ---------- GCN aggregation (shuffle-staged src+dinv) ----------
// FUSE_C2 (C=64): fused GCN2 matvec epilogue hw32 = v @ W_c2 (wave-local shfl).
// FUSE_LSM (C=32): fused log_softmax, writes f32 out.
template<int C, bool FUSE_LSM, bool FUSE_C2>
__global__ __launch_bounds__(256) void k_gcn_csr(
    const int* __restrict__ rowptr, const int* __restrict__ eid,
    const int* __restrict__ src, const float* __restrict__ dinv,
    const ushort* __restrict__ hw, const float* __restrict__ bias,
    void* __restrict__ outv, const ushort* __restrict__ w2)
{
  __shared__ ushort w2l[2048];         // [32][64] bf16 (used if FUSE_C2)
  if (FUSE_C2) {
    for (int i = threadIdx.x; i < 2048; i += 256) w2l[i] = w2[i];
    __syncthreads();
  }
  const int npb = 256 / C;
  int node = blockIdx.x * npb + threadIdx.x / C;
  int c = threadIdx.x & (C - 1);
  if (node >= NN) return;
  int b = rowptr[node], e = rowptr[node + 1];
  float acc = 0.f;
  for (int base = b; base < e; base += C) {
    int m = min(C, e - base);
    int sreg = 0;
    float dreg = 0.f;
    if (c < m) {
      int ed = eid[base + c];
      sreg = (ed < NE) ? src[ed] : node;
      dreg = dinv[sreg];
    }
    for (int i = 0; i < m; i++) {
      int s  = __shfl(sreg, i, C);
      float dv = __shfl(dreg, i, C);
      acc = fmaf(dv, b2f(hw[(ll)s * C + c]), acc);
    }
  }
  float v = acc * dinv[node] + bias[c];
  if (FUSE_C2) {
    // wave per node holds all 64 channels; hw32[j] = sum_c v[c] * W_c2[c][j]
    int j = c & 31, half = c >> 5;
    float part = 0.f;
    #pragma unroll 8
    for (int i = 0; i < 32; i++) {
      float vv = __shfl(v, half * 32 + i, 64);
      part = fmaf(vv, b2f(w2l[j * 64 + half * 32 + i]), part);
    }
    part += __shfl_xor(part, 32, 64);
    if (c < 32) ((ushort*)outv)[(ll)node * 32 + j] = f2b(part);
  } else if (!FUSE_LSM) {
    ((ushort*)outv)[(ll)node * C + c] = f2b(v);
  } else {
    float mx = v;
    #pragma unroll
    for (int o = 16; o > 0; o >>= 1) mx = fmaxf(mx, __shfl_xor(mx, o, 32));
    float s = expf(v - mx);
    #pragma unroll
    for (int o = 16; o > 0; o >>= 1) s += __shfl_xor(s, o, 32);
    ((float*)outv)[(ll)node * C + c] = v - mx - logf(s);
  }
}

extern "C" void kernel_launch(void* const* d_in, const int* in_sizes, int n_in,
                              void* d_out, int out_size, void* d_ws, size_t ws_size,
                              hipStream_t stream) {
  const float* x     = (const float*)d_in[0];
  const int*   ei    = (const int*)d_in[1];
  const float* W_l1  = (const float*)d_in[2];
  const float* b_l1  = (const float*)d_in[3];
  const float* W_r1  = (const float*)d_in[4];
  const float* W_l2  = (const float*)d_in[5];
  const float* b_l2  = (const float*)d_in[6];
  const float* W_r2  = (const float*)d_in[7];
  const float* W_g   = (const float*)d_in[8];
  const float* att_s = (const float*)d_in[9];
  const float* att_d = (const float*)d_in[10];
  const float* b_g   = (const float*)d_in[11];
  const float* W_c1  = (const float*)d_in[12];
  const float* b_c1  = (const float*)d_in[13];
  const float* W_c2  = (const float*)d_in[14];
  const float* b_c2  = (const float*)d_in[15];
  const float* W_res = (const float*)d_in[16];
  const float* b_res = (const float*)d_in[17];
  const int* src = ei;
  const int* dst = ei + NE;
  float* out = (float*)d_out;

  // ---- workspace layout (4-byte units) ----
  float* Wf = (float*)d_ws;
  size_t off = 0;
  auto take = [&](size_t n) { float* p = Wf + off; off += (n + 3) & ~(size_t)3; return p; };
  ushort* xb    = (ushort*)take((size_t)NN * 128);   // x bf16 [NN,256]
  ushort* C192  = (ushort*)take((size_t)NN * 96);    // [resx|xw1|xr1]
  ushort* h1    = (ushort*)take((size_t)NN * 32);    // [NN,64]
  ushort* C256  = (ushort*)take((size_t)NN * 128);   // [hw2|hr2]
  ushort* h2    = (ushort*)take((size_t)NN * 64);    // [NN,128]
  ushort* agg   = (ushort*)take((size_t)NN * 512);   // [NN,8,128] alpha-weighted h2
  ushort* hw64  = (ushort*)take((size_t)NN * 32);
  ushort* hw32  = (ushort*)take((size_t)NN * 16);
  ushort* Bt192 = (ushort*)take(192 * 256 / 2);
  ushort* Bt256 = (ushort*)take(256 * 64 / 2);
  ushort* BtG   = (ushort*)take(1024 * 128 / 2);
  ushort* Btc1  = (ushort*)take(64 * 1024 / 2);
  ushort* Btc2  = (ushort*)take(32 * 64 / 2);
  ushort* watt_t= (ushort*)take(16 * 128 / 2);       // [16,128] transposed W_g@att
  float* bias192 = take(192);
  float* bias256 = take(256);
  int*   icnt   = (int*)take(NN);
  int*   rowptr = (int*)take(NN + 1);
  int*   cur    = (int*)take(NN);
  int*   eidb   = (int*)take(NEF);
  int*   bsum   = (int*)take(NB1);
  int*   boff   = (int*)take(NB1);
  float* dinv   = take(NN);
  float* asd    = take((size_t)NN * 16);
  (void)ws_size; (void)in_sizes; (void)n_in; (void)out_size;

  auto nb = [](ll t) { return dim3((unsigned)((t + 255) / 256)); };

  // ---- setup first (also zeroes icnt): cast x, weights, bias packs, watt ----
  Prep pp;
  int base = 0;
  auto ent = [&](int i, const float* W, ushort* Bt, int N_, int K_) {
    pp.e[i] = {W, Bt, N_, K_, base}; base += N_ * K_;
  };
  ent(0, W_res, Bt192,             64, 256);
  ent(1, W_l1,  Bt192 + 64 * 256,  64, 256);
  ent(2, W_r1,  Bt192 + 128 * 256, 64, 256);
  ent(3, W_l2,  Bt256,             128, 64);
  ent(4, W_r2,  Bt256 + 128 * 64,  128, 64);
  ent(5, W_g,   BtG,               1024, 128);
  ent(6, W_c1,  Btc1,              64, 1024);
  ent(7, W_c2,  Btc2,              32, 64);
  pp.total = base;
  k_setup<<<nb((ll)NN * 64 + base + 256 + 2048 + NN), 256, 0, stream>>>(
      x, xb, pp, b_res, b_l1, b_l2, bias192, bias256, W_g, att_s, att_d, watt_t, icnt);

  // ---- CSR build (hierarchical 3-kernel scan — parallel across 79 blocks) ----
  k_counti<<<nb(NE), 256, 0, stream>>>(dst, icnt);
  k_scan1<<<NB1, 256, 0, stream>>>(icnt, rowptr, bsum);
  k_scan2<<<1, 128, 0, stream>>>(bsum, boff);
  k_scan3<<<nb(NN), 256, 0, stream>>>(rowptr, boff, cur, icnt, dinv);
  k_scatter<<<nb(NEF), 256, 0, stream>>>(dst, cur, eidb);

  // ---- SAGE1 (+residual): N=192 GEMM [resx|xw1|xr1], MF=4 ----
  gemm_mfma<4, 2, 256, false><<<dim3(3, 157), 256, 0, stream>>>(
      xb, Bt192, bias192, C192, NN, 192, 256);
  k_sage_csr<64, 192, true, false><<<nb((ll)NN * 64), 256, 0, stream>>>(
      rowptr, eidb, src, C192 + 64, C192 + 128, C192, h1, nullptr, nullptr);

  // ---- SAGE2: N=256 GEMM [hw2|hr2], MF=4; fused GAT score epilogue ----
  gemm_mfma<4, 2, 64, false><<<dim3(4, 157), 256, 0, stream>>>(
      h1, Bt256, bias256, C256, NN, 256, 64);
  k_sage_csr<128, 256, false, true><<<nb((ll)NN * 64), 256, 0, stream>>>(
      rowptr, eidb, src, C256, C256 + 128, nullptr, h2, watt_t, asd);

  // ---- GAT: fused softmax+agg, then fused staged W_g apply + GCN1 GEMM ----
  k_gat_agg<<<dim3(NN), 128, 0, stream>>>(
      rowptr, eidb, src, asd, h2, agg);
  k_gat_apply_gcn1<<<dim3(625), 256, 0, stream>>>(agg, BtG, Btc1, b_g, hw64);

  // ---- GCN1 agg (+fused GCN2 matvec), then GCN2 agg + fused log_softmax ----
  k_gcn_csr<64, false, true><<<nb((ll)NN * 64), 256, 0, stream>>>(
      rowptr, eidb, src, dinv, hw64, b_c1, hw32, Btc2);
  k_gcn_csr<32, true, false><<<nb((ll)NN * 32), 256, 0, stream>>>(
      rowptr, eidb, src, dinv, hw32, b_c2, out, nullptr);
}

// Round 17
// 219.007 us; speedup vs baseline: 1.0701x; 1.0701x over previous
//
#include <hip/hip_runtime.h>

#define NN 20000
#define NE 160000
#define NEF 180000          // edges + self loops
#define NB1 ((NN + 255) / 256)   // 79 scan blocks

typedef long long ll;
typedef __attribute__((ext_vector_type(4))) float f32x4;
typedef __attribute__((ext_vector_type(8))) short s16x8;

// ---------- bf16 helpers (round-to-nearest-even) ----------
static __device__ __forceinline__ float b2f(ushort u) {
  return __uint_as_float(((unsigned)u) << 16);
}
static __device__ __forceinline__ ushort f2b(float f) {
  unsigned u = __float_as_uint(f);
  return (ushort)((u + 0x7fffu + ((u >> 16) & 1u)) >> 16);
}

// ---------- bf16 MFMA GEMM: C[M,N] = A[M,K] @ Bt[N,K]^T (+bias) ----------
// 4 waves in 2x2; wave tile = (16*MF) x (16*NF); no LDS; compile-time K.
template<int MF, int NF, int K, bool F32OUT>
__global__ __launch_bounds__(256) void gemm_mfma(
    const ushort* __restrict__ A, const ushort* __restrict__ Bt,
    const float* __restrict__ bias, void* __restrict__ Cv,
    int M, int N, int lda)
{
  const int wid  = threadIdx.x >> 6;
  const int lane = threadIdx.x & 63;
  const int wr = wid >> 1, wc = wid & 1;
  const int bm = blockIdx.y * (32 * MF) + wr * (16 * MF);
  const int bn = blockIdx.x * (32 * NF) + wc * (16 * NF);
  const int lr = lane & 15;
  const int ko = (lane >> 4) * 8;

  const ushort* pa[MF];
  const ushort* pb[NF];
  #pragma unroll
  for (int i = 0; i < MF; i++) {
    int r = min(bm + i * 16 + lr, M - 1);
    pa[i] = A + (ll)r * lda + ko;
  }
  #pragma unroll
  for (int j = 0; j < NF; j++) {
    int c = min(bn + j * 16 + lr, N - 1);
    pb[j] = Bt + (ll)c * K + ko;
  }

  f32x4 acc[MF][NF];
  #pragma unroll
  for (int i = 0; i < MF; i++)
    #pragma unroll
    for (int j = 0; j < NF; j++) acc[i][j] = {0.f, 0.f, 0.f, 0.f};

  #pragma unroll
  for (int k = 0; k < K; k += 32) {
    s16x8 af[MF], bf[NF];
    #pragma unroll
    for (int i = 0; i < MF; i++) af[i] = *(const s16x8*)(pa[i] + k);
    #pragma unroll
    for (int j = 0; j < NF; j++) bf[j] = *(const s16x8*)(pb[j] + k);
    #pragma unroll
    for (int i = 0; i < MF; i++)
      #pragma unroll
      for (int j = 0; j < NF; j++)
        acc[i][j] = __builtin_amdgcn_mfma_f32_16x16x32_bf16(af[i], bf[j], acc[i][j], 0, 0, 0);
  }

  const int rq = (lane >> 4) * 4;
  #pragma unroll
  for (int i = 0; i < MF; i++) {
    #pragma unroll
    for (int j = 0; j < NF; j++) {
      int col = bn + j * 16 + lr;
      if (col >= N) continue;
      float bv = bias ? bias[col] : 0.f;
      int rbase = bm + i * 16 + rq;
      #pragma unroll
      for (int r = 0; r < 4; r++) {
        int row = rbase + r;
        if (row >= M) continue;
        float v = acc[i][j][r] + bv;
        if (F32OUT) ((float*)Cv)[(ll)row * N + col] = v;
        else        ((ushort*)Cv)[(ll)row * N + col] = f2b(v);
      }
    }
  }
}

// ---------- fused GAT-apply + GCN1 GEMM (all-heads A prestage + B prefetch) ----
// hw64 = relu(agg @ blockdiag(W_g) + b_g) @ W_c1, never materializing gat.
__global__ __launch_bounds__(256) void k_gat_apply_gcn1(
    const ushort* __restrict__ agg,   // [NN,1024] bf16 (8 heads x 128)
    const ushort* __restrict__ BtG,   // [1024,128]: BtG[c*128+k] = W_g[k,c]
    const ushort* __restrict__ Btc1,  // [64,1024]:  Btc1[n*1024+k] = W_c1[k,n]
    const float* __restrict__ b_g,    // [1024]
    ushort* __restrict__ hw64)        // [NN,64] bf16
{
  __shared__ ushort At[2][32 * 128];  // A windows, granule^=(row&7) swizzle
  __shared__ ushort gt[2][32][72];    // gat tiles (+pad)
  const int t    = threadIdx.x;
  const int wc   = t >> 6;            // wave = col strip 0..3
  const int lane = t & 63;
  const int bm = blockIdx.x * 32;
  const int lr = lane & 15;
  const int q  = lane >> 4;
  const int ko = q * 8;
  const int rq = q * 4;

  // staging identity: thread = (row 0..31, colgroup 0..7), 2x16B granules
  const int srow = t >> 3;
  const int scg  = t & 7;
  const ushort* sg = agg + (ll)min(bm + srow, NN - 1) * 1024 + scg * 16;
  const int w0 = srow * 128 + (((2 * scg)     ^ (srow & 7)) * 8);
  const int w1 = srow * 128 + (((2 * scg + 1) ^ (srow & 7)) * 8);

  // ---- stage ALL heads' A into registers upfront ----
  s16x8 ar[8][2];
  #pragma unroll
  for (int h = 0; h < 8; h++) {
    ar[h][0] = *(const s16x8*)(sg + h * 128);
    ar[h][1] = *(const s16x8*)(sg + h * 128 + 8);
  }

  // ---- B double-buffer registers; preload ct = 0 ----
  s16x8 b1[2][4];                     // phase-1 W_g fragments
  s16x8 b2[2][2];                     // phase-2 W_c1 fragments
  float bvs[2];
  {
    const int cg = wc * 16 + lr;
    const ushort* pb = BtG + (ll)cg * 128 + ko;
    b1[0][0] = *(const s16x8*)(pb);
    b1[0][1] = *(const s16x8*)(pb + 32);
    b1[0][2] = *(const s16x8*)(pb + 64);
    b1[0][3] = *(const s16x8*)(pb + 96);
    const ushort* qb = Btc1 + (ll)cg * 1024 + ko;
    b2[0][0] = *(const s16x8*)(qb);
    b2[0][1] = *(const s16x8*)(qb + 32);
    bvs[0] = b_g[cg];
  }

  f32x4 o0 = {0.f, 0.f, 0.f, 0.f}, o1 = o0;

  #pragma unroll
  for (int h = 0; h < 8; h++) {
    *(s16x8*)&At[h & 1][w0] = ar[h][0];
    *(s16x8*)&At[h & 1][w1] = ar[h][1];
    __syncthreads();
    #pragma unroll
    for (int it = 0; it < 2; it++) {
      const int ct = 2 * h + it;       // compile-time
      const int cur = it, nxt = it ^ 1;
      if (ct < 15) {                   // prefetch next ct's B + bias
        const int cg2 = (ct + 1) * 64 + wc * 16 + lr;
        const ushort* pb2 = BtG + (ll)cg2 * 128 + ko;
        b1[nxt][0] = *(const s16x8*)(pb2);
        b1[nxt][1] = *(const s16x8*)(pb2 + 32);
        b1[nxt][2] = *(const s16x8*)(pb2 + 64);
        b1[nxt][3] = *(const s16x8*)(pb2 + 96);
        const ushort* qb2 = Btc1 + (ll)(wc * 16 + lr) * 1024 + (ct + 1) * 64 + ko;
        b2[nxt][0] = *(const s16x8*)(qb2);
        b2[nxt][1] = *(const s16x8*)(qb2 + 32);
        bvs[nxt] = b_g[cg2];
      }
      f32x4 g0 = {0.f, 0.f, 0.f, 0.f}, g1 = g0;
      #pragma unroll
      for (int k = 0; k < 4; k++) {
        const int gi = (k * 4 + q) ^ (lr & 7);
        s16x8 a0 = *(const s16x8*)&At[h & 1][lr        * 128 + gi * 8];
        s16x8 a1 = *(const s16x8*)&At[h & 1][(16 + lr) * 128 + gi * 8];
        g0 = __builtin_amdgcn_mfma_f32_16x16x32_bf16(a0, b1[cur][k], g0, 0, 0, 0);
        g1 = __builtin_amdgcn_mfma_f32_16x16x32_bf16(a1, b1[cur][k], g1, 0, 0, 0);
      }
      float bv = bvs[cur];
      #pragma unroll
      for (int r = 0; r < 4; r++) {
        gt[it][rq + r][wc * 16 + lr]      = f2b(fmaxf(g0[r] + bv, 0.f));
        gt[it][16 + rq + r][wc * 16 + lr] = f2b(fmaxf(g1[r] + bv, 0.f));
      }
      __syncthreads();
      {
        s16x8 a0 = *(const s16x8*)&gt[it][lr][ko];
        s16x8 a1 = *(const s16x8*)&gt[it][16 + lr][ko];
        o0 = __builtin_amdgcn_mfma_f32_16x16x32_bf16(a0, b2[cur][0], o0, 0, 0, 0);
        o1 = __builtin_amdgcn_mfma_f32_16x16x32_bf16(a1, b2[cur][0], o1, 0, 0, 0);
        s16x8 a2 = *(const s16x8*)&gt[it][lr][32 + ko];
        s16x8 a3 = *(const s16x8*)&gt[it][16 + lr][32 + ko];
        o0 = __builtin_amdgcn_mfma_f32_16x16x32_bf16(a2, b2[cur][1], o0, 0, 0, 0);
        o1 = __builtin_amdgcn_mfma_f32_16x16x32_bf16(a3, b2[cur][1], o1, 0, 0, 0);
      }
    }
  }
  int col = wc * 16 + lr;
  #pragma unroll
  for (int r = 0; r < 4; r++) {
    int row0 = bm + rq + r, row1 = bm + 16 + rq + r;
    if (row0 < NN) hw64[(ll)row0 * 64 + col] = f2b(o0[r]);
    if (row1 < NN) hw64[(ll)row1 * 64 + col] = f2b(o1[r]);
  }
}

// ---------- fused setup: x cast, weight transpose+cast, bias packs, watt, zero icnt --
struct PrepEnt { const float* W; ushort* Bt; int N; int K; int base; };
struct Prep { PrepEnt e[8]; int total; };

__global__ void k_setup(const float* __restrict__ x, ushort* __restrict__ xb, Prep p,
                        const float* __restrict__ b_res, const float* __restrict__ b_l1,
                        const float* __restrict__ b_l2, float* __restrict__ bias192,
                        float* __restrict__ bias256,
                        const float* __restrict__ W_g, const float* __restrict__ att_s,
                        const float* __restrict__ att_d, ushort* __restrict__ watt_t,
                        int* __restrict__ icnt) {
  ll t = (ll)blockIdx.x * 256 + threadIdx.x;
  const ll T0 = (ll)NN * 64;          // x cast: 4 floats each
  if (t < T0) {
    ll i = t * 4;
    float4 v = *(const float4*)(x + i);
    ushort4 o;
    o.x = f2b(v.x); o.y = f2b(v.y); o.z = f2b(v.z); o.w = f2b(v.w);
    *(ushort4*)(xb + i) = o;
    return;
  }
  t -= T0;
  if (t < p.total) {
    int tt = (int)t;
    #pragma unroll
    for (int i = 0; i < 8; i++) {
      int sz = p.e[i].N * p.e[i].K;
      if (tt >= p.e[i].base && tt < p.e[i].base + sz) {
        int loc = tt - p.e[i].base;
        int n = loc / p.e[i].K, k = loc - n * p.e[i].K;
        p.e[i].Bt[loc] = f2b(p.e[i].W[(ll)k * p.e[i].N + n]);
      }
    }
    return;
  }
  t -= p.total;
  if (t < 256) {
    int tt = (int)t;
    if (tt < 64) bias192[tt] = b_res[tt];
    else if (tt < 128) bias192[tt] = 0.f;
    else if (tt < 192) bias192[tt] = b_l1[tt - 128];
    bias256[tt] = (tt < 128) ? 0.f : b_l2[tt - 128];
    return;
  }
  t -= 256;
  if (t < 2048) {   // watt_t[col][k] = bf16( dot(W_g[k, h*128: ], att_{s|d}[h, :]) )
    int k = (int)t >> 4;
    int col = (int)t & 15;
    int h = col & 7;
    const float* av = (col < 8) ? (att_s + h * 128) : (att_d + h * 128);
    const float* wrow = W_g + (ll)k * 1024 + h * 128;
    float s = 0.f;
    for (int j = 0; j < 128; j++) s += wrow[j] * av[j];
    watt_t[col * 128 + k] = f2b(s);
    return;
  }
  t -= 2048;
  if (t < NN) icnt[t] = 0;
}

// ---------- CSR build ----------
__global__ void k_counti(const int* __restrict__ dst, int* __restrict__ icnt) {
  int e = blockIdx.x * 256 + threadIdx.x;
  if (e < NE) atomicAdd(&icnt[dst[e]], 1);
}

__global__ __launch_bounds__(256) void k_scan1(const int* __restrict__ icnt,
                                               int* __restrict__ rowptr,
                                               int* __restrict__ bsum) {
  __shared__ int sd[256];
  int t = threadIdx.x;
  int i = blockIdx.x * 256 + t;
  int v = (i < NN) ? icnt[i] + 1 : 0;   // +1 self loop
  sd[t] = v;
  __syncthreads();
  #pragma unroll
  for (int o = 1; o < 256; o <<= 1) {
    int u = (t >= o) ? sd[t - o] : 0;
    __syncthreads();
    sd[t] += u;
    __syncthreads();
  }
  if (i < NN) rowptr[i] = sd[t] - v;    // block-local exclusive
  if (t == 255) bsum[blockIdx.x] = sd[255];
}

__global__ __launch_bounds__(128) void k_scan2(const int* __restrict__ bsum,
                                               int* __restrict__ boff) {
  __shared__ int sd[128];
  int t = threadIdx.x;
  int v = (t < NB1) ? bsum[t] : 0;
  sd[t] = v;
  __syncthreads();
  #pragma unroll
  for (int o = 1; o < 128; o <<= 1) {
    int u = (t >= o) ? sd[t - o] : 0;
    __syncthreads();
    sd[t] += u;
    __syncthreads();
  }
  if (t < NB1) boff[t] = sd[t] - v;
}

__global__ void k_scan3(int* __restrict__ rowptr, const int* __restrict__ boff,
                        int* __restrict__ cur, const int* __restrict__ icnt,
                        float* __restrict__ dinv) {
  int i = blockIdx.x * 256 + threadIdx.x;
  if (i >= NN) return;
  int r = rowptr[i] + boff[i >> 8];
  rowptr[i] = r;
  cur[i] = r;
  dinv[i] = rsqrtf((float)icnt[i] + 1.0f);
  if (i == 0) rowptr[NN] = NEF;
}

__global__ void k_scatter(const int* __restrict__ dst, int* __restrict__ cur,
                          int* __restrict__ eid) {
  int t = blockIdx.x * 256 + threadIdx.x;
  if (t >= NEF) return;
  int d = (t < NE) ? dst[t] : t - NE;
  int p = atomicAdd(&cur[d], 1);
  eid[p] = t;
}

// ---------- SAGE aggregation: shuffle-staged gather + mean + lin_r + relu (+res) --
template<int C, int STRIDE, bool ADD_RES>
__global__ __launch_bounds__(256) void k_sage_csr(
    const int* __restrict__ rowptr, const int* __restrict__ eid,
    const int* __restrict__ src, const ushort* __restrict__ feat,
    const ushort* __restrict__ linr, const ushort* __restrict__ resx,
    ushort* __restrict__ out)
{
  int node = blockIdx.x * 4 + (threadIdx.x >> 6);
  int lane = threadIdx.x & 63;
  if (node >= NN) return;
  int b = rowptr[node], e = rowptr[node + 1];
  float a0 = 0.f, a1 = 0.f;
  int n = 0;
  for (int base = b; base < e; base += 64) {
    int m = min(64, e - base);
    int sreg = -1;
    if (lane < m) {
      int ed = eid[base + lane];
      sreg = (ed < NE) ? src[ed] : -1;   // self loop excluded from SAGE mean
    }
    for (int i = 0; i < m; i++) {
      int s = __shfl(sreg, i);
      if (s >= 0) {
        a0 += b2f(feat[(ll)s * STRIDE + lane]);
        if (C == 128) a1 += b2f(feat[(ll)s * STRIDE + lane + 64]);
        n++;
      }
    }
  }
  float inv = 1.f / fmaxf((float)n, 1.f);
  {
    float v = a0 * inv + b2f(linr[(ll)node * STRIDE + lane]);
    v = fmaxf(v, 0.f);
    if (ADD_RES) v += b2f(resx[(ll)node * STRIDE + lane]);
    out[(ll)node * C + lane] = f2b(v);
  }
  if (C == 128) {
    float v = a1 * inv + b2f(linr[(ll)node * STRIDE + lane + 64]);
    v = fmaxf(v, 0.f);
    out[(ll)node * C + lane + 64] = f2b(v);
  }
}

// ---------- fused GAT softmax + aggregation in h2-space ----------
// agg[n,h,c] = (1/den_h) sum_e exp(score_e,h - max_h) * h2[src_e, c]
// Block per node, 128 threads. Flash-style online max/sum across 64-edge chunks.
__global__ __launch_bounds__(128) void k_gat_agg(
    const int* __restrict__ rowptr, const int* __restrict__ eid,
    const int* __restrict__ src, const float* __restrict__ asd,
    const ushort* __restrict__ h2b, ushort* __restrict__ agg)
{
  __shared__ int s_l[64];
  __shared__ float al[64 * 8];
  __shared__ float adl[8];
  __shared__ float mrun[8], srun[8], fac[8];
  int node = blockIdx.x;
  int c = threadIdx.x;                 // channel 0..127
  int b = rowptr[node], e = rowptr[node + 1];
  if (c < 8) {
    adl[c] = asd[(ll)node * 16 + 8 + c];
    mrun[c] = -3.0e38f;
    srun[c] = 0.f;
  }
  float acc[8] = {0.f, 0.f, 0.f, 0.f, 0.f, 0.f, 0.f, 0.f};
  for (int c0 = b; c0 < e; c0 += 64) {
    int m = min(64, e - c0);
    if (c < m) { int ed = eid[c0 + c]; s_l[c] = (ed < NE) ? src[ed] : node; }
    __syncthreads();
    // scores (leaky-relu) for this chunk
    for (int idx = c; idx < m * 8; idx += 128) {
      int i = idx >> 3, h = idx & 7;
      float v = asd[(ll)s_l[i] * 16 + h] + adl[h];
      al[idx] = (v > 0.f) ? v : 0.2f * v;
    }
    __syncthreads();
    // per-head chunk max + rescale factor (threads 0..7)
    if (c < 8) {
      float cm = mrun[c];
      for (int i = 0; i < m; i++) cm = fmaxf(cm, al[i * 8 + c]);
      fac[c] = __expf(mrun[c] - cm);
      mrun[c] = cm;
    }
    __syncthreads();
    // exponentiate in place
    for (int idx = c; idx < m * 8; idx += 128) {
      int h = idx & 7;
      al[idx] = __expf(al[idx] - mrun[h]);
    }
    __syncthreads();
    // per-head sum update
    if (c < 8) {
      float cs = 0.f;
      for (int i = 0; i < m; i++) cs += al[i * 8 + c];
      srun[c] = srun[c] * fac[c] + cs;
    }
    // rescale accumulators, then aggregate this chunk
    #pragma unroll
    for (int h = 0; h < 8; h++) acc[h] *= fac[h];
    for (int i = 0; i < m; i++) {
      float v = b2f(h2b[(ll)s_l[i] * 128 + c]);
      float4 aa = *(const float4*)&al[i * 8];
      float4 ab = *(const float4*)&al[i * 8 + 4];
      acc[0] = fmaf(aa.x, v, acc[0]);
      acc[1] = fmaf(aa.y, v, acc[1]);
      acc[2] = fmaf(aa.z, v, acc[2]);
      acc[3] = fmaf(aa.w, v, acc[3]);
      acc[4] = fmaf(ab.x, v, acc[4]);
      acc[5] = fmaf(ab.y, v, acc[5]);
      acc[6] = fmaf(ab.z, v, acc[6]);
      acc[7] = fmaf(ab.w, v, acc[7]);
    }
    __syncthreads();
  }
  #pragma unroll
  for (int h = 0; h < 8; h++)
    agg[(ll)node * 1024 + h * 128 + c] = f2b(acc[h] / srun[h]);
}

// ---------- GCN aggregation (shuffle-staged src+dinv); optional fused log_softmax --
template<int C, bool FUSE_LSM>
__global__ __launch_bounds__(256) void k_gcn_csr(
    const int* __restrict__ rowptr, const int* __restrict__ eid,
    const int* __restrict__ src, const float* __restrict__ dinv,
    const ushort* __restrict__ hw, const float* __restrict__ bias,
    void* __restrict__ outv)
{
  const int npb = 256 / C;
  int node = blockIdx.x * npb + threadIdx.x / C;
  int c = threadIdx.x & (C - 1);
  if (node >= NN) return;
  int b = rowptr[node], e = rowptr[node + 1];
  float acc = 0.f;
  for (int base = b; base < e; base += C) {
    int m = min(C, e - base);
    int sreg = 0;
    float dreg = 0.f;
    if (c < m) {
      int ed = eid[base + c];
      sreg = (ed < NE) ? src[ed] : node;
      dreg = dinv[sreg];
    }
    for (int i = 0; i < m; i++) {
      int s  = __shfl(sreg, i, C);
      float dv = __shfl(dreg, i, C);
      acc = fmaf(dv, b2f(hw[(ll)s * C + c]), acc);
    }
  }
  float v = acc * dinv[node] + bias[c];
  if (!FUSE_LSM) {
    ((ushort*)outv)[(ll)node * C + c] = f2b(v);
  } else {
    float mx = v;
    #pragma unroll
    for (int o = 16; o > 0; o >>= 1) mx = fmaxf(mx, __shfl_xor(mx, o, 32));
    float s = expf(v - mx);
    #pragma unroll
    for (int o = 16; o > 0; o >>= 1) s += __shfl_xor(s, o, 32);
    ((float*)outv)[(ll)node * C + c] = v - mx - logf(s);
  }
}

extern "C" void kernel_launch(void* const* d_in, const int* in_sizes, int n_in,
                              void* d_out, int out_size, void* d_ws, size_t ws_size,
                              hipStream_t stream) {
  const float* x     = (const float*)d_in[0];
  const int*   ei    = (const int*)d_in[1];
  const float* W_l1  = (const float*)d_in[2];
  const float* b_l1  = (const float*)d_in[3];
  const float* W_r1  = (const float*)d_in[4];
  const float* W_l2  = (const float*)d_in[5];
  const float* b_l2  = (const float*)d_in[6];
  const float* W_r2  = (const float*)d_in[7];
  const float* W_g   = (const float*)d_in[8];
  const float* att_s = (const float*)d_in[9];
  const float* att_d = (const float*)d_in[10];
  const float* b_g   = (const float*)d_in[11];
  const float* W_c1  = (const float*)d_in[12];
  const float* b_c1  = (const float*)d_in[13];
  const float* W_c2  = (const float*)d_in[14];
  const float* b_c2  = (const float*)d_in[15];
  const float* W_res = (const float*)d_in[16];
  const float* b_res = (const float*)d_in[17];
  const int* src = ei;
  const int* dst = ei + NE;
  float* out = (float*)d_out;

  // ---- workspace layout (4-byte units) ----
  float* Wf = (float*)d_ws;
  size_t off = 0;
  auto take = [&](size_t n) { float* p = Wf + off; off += (n + 3) & ~(size_t)3; return p; };
  ushort* xb    = (ushort*)take((size_t)NN * 128);   // x bf16 [NN,256]
  ushort* C192  = (ushort*)take((size_t)NN * 96);    // [resx|xw1|xr1]
  ushort* h1    = (ushort*)take((size_t)NN * 32);    // [NN,64]
  ushort* C256  = (ushort*)take((size_t)NN * 128);   // [hw2|hr2]
  ushort* h2    = (ushort*)take((size_t)NN * 64);    // [NN,128]
  ushort* agg   = (ushort*)take((size_t)NN * 512);   // [NN,8,128] alpha-weighted h2
  ushort* hw64  = (ushort*)take((size_t)NN * 32);
  ushort* acc64 = (ushort*)take((size_t)NN * 32);
  ushort* hw32  = (ushort*)take((size_t)NN * 16);
  ushort* Bt192 = (ushort*)take(192 * 256 / 2);
  ushort* Bt256 = (ushort*)take(256 * 64 / 2);
  ushort* BtG   = (ushort*)take(1024 * 128 / 2);
  ushort* Btc1  = (ushort*)take(64 * 1024 / 2);
  ushort* Btc2  = (ushort*)take(32 * 64 / 2);
  ushort* watt_t= (ushort*)take(16 * 128 / 2);       // [16,128] transposed W_g@att
  float* bias192 = take(192);
  float* bias256 = take(256);
  int*   icnt   = (int*)take(NN);
  int*   rowptr = (int*)take(NN + 1);
  int*   cur    = (int*)take(NN);
  int*   eidb   = (int*)take(NEF);
  int*   bsum   = (int*)take(NB1);
  int*   boff   = (int*)take(NB1);
  float* dinv   = take(NN);
  float* asd    = take((size_t)NN * 16);
  (void)ws_size; (void)in_sizes; (void)n_in; (void)out_size;

  auto nb = [](ll t) { return dim3((unsigned)((t + 255) / 256)); };

  // ---- setup first (also zeroes icnt): cast x, weights, bias packs, watt ----
  Prep pp;
  int base = 0;
  auto ent = [&](int i, const float* W, ushort* Bt, int N_, int K_) {
    pp.e[i] = {W, Bt, N_, K_, base}; base += N_ * K_;
  };
  ent(0, W_res, Bt192,             64, 256);
  ent(1, W_l1,  Bt192 + 64 * 256,  64, 256);
  ent(2, W_r1,  Bt192 + 128 * 256, 64, 256);
  ent(3, W_l2,  Bt256,             128, 64);
  ent(4, W_r2,  Bt256 + 128 * 64,  128, 64);
  ent(5, W_g,   BtG,               1024, 128);
  ent(6, W_c1,  Btc1,              64, 1024);
  ent(7, W_c2,  Btc2,              32, 64);
  pp.total = base;
  k_setup<<<nb((ll)NN * 64 + base + 256 + 2048 + NN), 256, 0, stream>>>(
      x, xb, pp, b_res, b_l1, b_l2, bias192, bias256, W_g, att_s, att_d, watt_t, icnt);

  // ---- CSR build (hierarchical 3-kernel scan — parallel across 79 blocks) ----
  k_counti<<<nb(NE), 256, 0, stream>>>(dst, icnt);
  k_scan1<<<NB1, 256, 0, stream>>>(icnt, rowptr, bsum);
  k_scan2<<<1, 128, 0, stream>>>(bsum, boff);
  k_scan3<<<nb(NN), 256, 0, stream>>>(rowptr, boff, cur, icnt, dinv);
  k_scatter<<<nb(NEF), 256, 0, stream>>>(dst, cur, eidb);

  // ---- SAGE1 (+residual): N=192 GEMM [resx|xw1|xr1], MF=4 ----
  gemm_mfma<4, 2, 256, false><<<dim3(3, 157), 256, 0, stream>>>(
      xb, Bt192, bias192, C192, NN, 192, 256);
  k_sage_csr<64, 192, true><<<nb((ll)NN * 64), 256, 0, stream>>>(
      rowptr, eidb, src, C192 + 64, C192 + 128, C192, h1);

  // ---- SAGE2: N=256 GEMM [hw2|hr2], MF=4 ----
  gemm_mfma<4, 2, 64, false><<<dim3(4, 157), 256, 0, stream>>>(
      h1, Bt256, bias256, C256, NN, 256, 64);
  k_sage_csr<128, 256, false><<<nb((ll)NN * 64), 256, 0, stream>>>(
      rowptr, eidb, src, C256, C256 + 128, nullptr, h2);

  // ---- GAT: scores via tiny N=16 GEMM (f32 out, MF=4), fused softmax+agg,
  //      then fused staged W_g apply + GCN1 GEMM ----
  gemm_mfma<4, 1, 128, true><<<dim3(1, 157), 256, 0, stream>>>(
      h2, watt_t, nullptr, asd, NN, 16, 128);
  k_gat_agg<<<dim3(NN), 128, 0, stream>>>(
      rowptr, eidb, src, asd, h2, agg);
  k_gat_apply_gcn1<<<dim3(625), 256, 0, stream>>>(agg, BtG, Btc1, b_g, hw64);
  k_gcn_csr<64, false><<<nb((ll)NN * 64), 256, 0, stream>>>(
      rowptr, eidb, src, dinv, hw64, b_c1, acc64);

  // ---- GCN2 + fused log_softmax, MF=4 ----
  gemm_mfma<4, 1, 64, false><<<dim3(1, 157), 256, 0, stream>>>(
      acc64, Btc2, nullptr, hw32, NN, 32, 64);
  k_gcn_csr<32, true><<<nb((ll)NN * 32), 256, 0, stream>>>(
      rowptr, eidb, src, dinv, hw32, b_c2, out);
}